// Round 5
// baseline (905.018 us; speedup 1.0000x reference)
//
#include <hip/hip_runtime.h>
#include <stdint.h>

#define DEVI __device__ __forceinline__

typedef unsigned short u16;
typedef unsigned int u32;
typedef __attribute__((ext_vector_type(4))) unsigned short u16x4;
typedef __attribute__((ext_vector_type(8))) unsigned short u16x8;
typedef __attribute__((ext_vector_type(4))) float f32x4;
typedef __attribute__((ext_vector_type(8))) _Float16 f16x8;

static constexpr int NT = 4096;   // tokens
static constexpr int D  = 512;    // channels per head
static constexpr int NH = 4;      // heads
static constexpr int KS = 4;      // split-K factor for PV GEMMs

DEVI u16 f2h(float f) {
  _Float16 h = (_Float16)f;
  union { _Float16 h; u16 u; } v; v.h = h;
  return v.u;
}

// order-preserving float<->uint for atomicMax on floats (all finite values encode > 0)
DEVI u32 enc_ord(float f) {
  u32 u = __float_as_uint(f);
  return (u & 0x80000000u) ? ~u : (u | 0x80000000u);
}
DEVI float dec_ord(u32 k) {
  u32 u = (k & 0x80000000u) ? (k ^ 0x80000000u) : ~k;
  return __uint_as_float(u);
}

DEVI void gld_lds16(const u16* g, u16* l) {
  __builtin_amdgcn_global_load_lds((const __attribute__((address_space(1))) void*)g,
                                   (__attribute__((address_space(3))) void*)l, 16, 0, 0);
}

enum { OUT_F32 = 0, OUT_F16 = 2, OUT_RES = 3, OUT_SMAX = 4 };

// C[M,N] = A[M,K] @ B[N,K]^T  (f16 in, f32 acc). 128x128 tile, BK=32, 4 waves.
// OUT_SMAX: write f16 C and update global row/col max (ordered-u32 atomics).
template<int OUT>
__global__ __launch_bounds__(256)
void gemm_bt(const u16* __restrict__ A, int lda, size_t zsA,
             const u16* __restrict__ B, int ldb, size_t zsB,
             void* __restrict__ Cp, int ldc, size_t zsC,
             const float* __restrict__ res, int K,
             u32* __restrict__ rmg, u32* __restrict__ cmg)
{
  __shared__ u16 As[128 * 32];
  __shared__ u16 Bs[128 * 32];
  __shared__ u32 rmaxs[128], cmaxs[128];
  A += blockIdx.z * zsA;
  B += blockIdx.z * zsB;
  const int tid = threadIdx.x;
  const int lane = tid & 63, w = tid >> 6;
  const int wr = w >> 1, wc = w & 1;
  const int m0 = blockIdx.y * 128, n0 = blockIdx.x * 128;

  if (OUT == OUT_SMAX && tid < 128) { rmaxs[tid] = 0u; cmaxs[tid] = 0u; }

  f32x4 acc[4][4] = {};

  for (int k0 = 0; k0 < K; k0 += 32) {
    __syncthreads();
#pragma unroll
    for (int p = 0; p < 2; ++p) {
      int id = p * 256 + tid;
      int row = id >> 2, q = id & 3;
      gld_lds16(A + (size_t)(m0 + row) * lda + k0 + q * 8, As + id * 8);
      gld_lds16(B + (size_t)(n0 + row) * ldb + k0 + q * 8, Bs + id * 8);
    }
    __syncthreads();
    f16x8 af[4], bfv[4];
#pragma unroll
    for (int i = 0; i < 4; ++i)
      af[i] = *(const f16x8*)(As + (wr * 64 + i * 16 + (lane & 15)) * 32 + (lane >> 4) * 8);
#pragma unroll
    for (int i = 0; i < 4; ++i)
      bfv[i] = *(const f16x8*)(Bs + (wc * 64 + i * 16 + (lane & 15)) * 32 + (lane >> 4) * 8);
#pragma unroll
    for (int i = 0; i < 4; ++i)
#pragma unroll
      for (int j = 0; j < 4; ++j)
        acc[i][j] = __builtin_amdgcn_mfma_f32_16x16x32_f16(af[i], bfv[j], acc[i][j], 0, 0, 0);
  }

#pragma unroll
  for (int i = 0; i < 4; ++i) {
    int rl0 = wr * 64 + i * 16 + (lane >> 4) * 4;
#pragma unroll
    for (int j = 0; j < 4; ++j) {
      int cl = wc * 64 + j * 16 + (lane & 15);
      int c = n0 + cl;
#pragma unroll
      for (int e = 0; e < 4; ++e) {
        size_t idx = blockIdx.z * zsC + (size_t)(m0 + rl0 + e) * ldc + c;
        float v = acc[i][j][e];
        if (OUT == OUT_F32)  ((float*)Cp)[idx] = v;
        if (OUT == OUT_F16)  ((u16*)Cp)[idx] = f2h(v);
        if (OUT == OUT_RES)  ((float*)Cp)[idx] = res[idx] + v;
        if (OUT == OUT_SMAX) ((u16*)Cp)[idx] = f2h(v);
      }
    }
  }

  if (OUT == OUT_SMAX) {
    // row maxes: reduce over j in-reg, then LDS atomic per (i,e)
#pragma unroll
    for (int i = 0; i < 4; ++i) {
      int rl0 = wr * 64 + i * 16 + (lane >> 4) * 4;
#pragma unroll
      for (int e = 0; e < 4; ++e) {
        float m = fmaxf(fmaxf(acc[i][0][e], acc[i][1][e]), fmaxf(acc[i][2][e], acc[i][3][e]));
        atomicMax(&rmaxs[rl0 + e], enc_ord(m));
      }
    }
    // col maxes: reduce over (i,e) in-reg, then LDS atomic per j
#pragma unroll
    for (int j = 0; j < 4; ++j) {
      float m = -3e38f;
#pragma unroll
      for (int i = 0; i < 4; ++i)
#pragma unroll
        for (int e = 0; e < 4; ++e) m = fmaxf(m, acc[i][j][e]);
      atomicMax(&cmaxs[wc * 64 + j * 16 + (lane & 15)], enc_ord(m));
    }
    __syncthreads();
    if (tid < 128) {
      atomicMax(rmg + m0 + tid, rmaxs[tid]);
      atomicMax(cmg + n0 + tid, cmaxs[tid]);
    }
  }
}

// one pass over f16 S: P1 = exp(S - rowmax) (row-major), P2T = exp(S - colmax) transposed,
// + partial row sums (seg = m-tile) and partial col sums (seg = n-tile)
__global__ __launch_bounds__(256)
void makeP(const u16* __restrict__ S,
           const u32* __restrict__ rowm_u, const u32* __restrict__ colm_u,
           u16* __restrict__ P1, u16* __restrict__ P2T,
           float* __restrict__ psumR, float* __restrict__ psumC)
{
  __shared__ u16 T[128][136];
  __shared__ float ps[16][128];
  __shared__ float rsum[128];
  __shared__ float rmv[128];
  const int tid = threadIdx.x;
  const int m0 = blockIdx.x * 128, n0 = blockIdx.y * 128;
  if (tid < 128) rmv[tid] = dec_ord(rowm_u[n0 + tid]);
  const int g = tid >> 4, c8 = (tid & 15) * 8;
  float cm[8], cs[8] = {};
#pragma unroll
  for (int j = 0; j < 8; ++j) cm[j] = dec_ord(colm_u[m0 + c8 + j]);
  __syncthreads();
#pragma unroll
  for (int it = 0; it < 8; ++it) {
    int r = it * 16 + g;
    f16x8 sv = *(const f16x8*)(S + (size_t)(n0 + r) * NT + m0 + c8);
    float m = rmv[r];
    u16x8 o1, o2;
    float rs = 0.f;
#pragma unroll
    for (int j = 0; j < 8; ++j) {
      float s = (float)sv[j];
      float p1 = __expf(s - m);
      rs += p1;
      o1[j] = f2h(p1);
      float p2 = __expf(s - cm[j]);
      cs[j] += p2;
      o2[j] = f2h(p2);
    }
    *(u16x8*)(P1 + (size_t)(n0 + r) * NT + m0 + c8) = o1;
    *(u16x8*)&T[r][c8] = o2;
#pragma unroll
    for (int o = 8; o; o >>= 1) rs += __shfl_xor(rs, o);
    if ((tid & 15) == 0) rsum[r] = rs;
  }
#pragma unroll
  for (int j = 0; j < 8; ++j) ps[g][c8 + j] = cs[j];
  __syncthreads();
  if (tid < 128) {
    float s = 0.f;
#pragma unroll
    for (int q = 0; q < 16; ++q) s += ps[q][tid];
    psumC[(size_t)blockIdx.y * NT + m0 + tid] = s;
    psumR[(size_t)blockIdx.x * NT + n0 + tid] = rsum[tid];
  }
#pragma unroll
  for (int it = 0; it < 8; ++it) {
    int ml = it * 16 + g, n8 = (tid & 15) * 8;
    u16x8 o;
#pragma unroll
    for (int j = 0; j < 8; ++j) o[j] = T[n8 + j][ml];
    *(u16x8*)(P2T + (size_t)(m0 + ml) * NT + n0 + n8) = o;
  }
}

// rowl[i] = sum_g psumR[g][i]; csum[i] = sum_g psumC[g][i]
__global__ __launch_bounds__(256)
void sum_reduce(const float* __restrict__ psumR, const float* __restrict__ psumC,
                float* __restrict__ rowl, float* __restrict__ csum)
{
  int i = blockIdx.x * 256 + threadIdx.x;
  float a = 0.f, b = 0.f;
#pragma unroll
  for (int g = 0; g < 32; ++g) {
    a += psumR[(size_t)g * NT + i];
    b += psumC[(size_t)g * NT + i];
  }
  rowl[i] = a;
  csum[i] = b;
}

// C[M,N] += (0.25/l[m]) * (P[M, kb:kb+Ksl] @ B[N, kb:kb+Ksl]^T)  via f32 atomics
__global__ __launch_bounds__(256)
void gemm_ps(const u16* __restrict__ P, int lda,
             const u16* __restrict__ B, int ldb,
             float* __restrict__ C, int ldc,
             const float* __restrict__ l, int Ksl)
{
  __shared__ u16 As[128 * 32];
  __shared__ u16 Bs[128 * 32];
  const int tid = threadIdx.x;
  const int lane = tid & 63, w = tid >> 6;
  const int wr = w >> 1, wc = w & 1;
  const int m0 = blockIdx.y * 128, n0 = blockIdx.x * 128;
  const int kb = blockIdx.z * Ksl;

  f32x4 acc[4][4] = {};

  for (int k0 = 0; k0 < Ksl; k0 += 32) {
    __syncthreads();
#pragma unroll
    for (int p = 0; p < 2; ++p) {
      int id = p * 256 + tid;
      int row = id >> 2, q = id & 3;
      gld_lds16(P + (size_t)(m0 + row) * lda + kb + k0 + q * 8, As + id * 8);
      gld_lds16(B + (size_t)(n0 + row) * ldb + kb + k0 + q * 8, Bs + id * 8);
    }
    __syncthreads();
    f16x8 af[4], bfv[4];
#pragma unroll
    for (int i = 0; i < 4; ++i)
      af[i] = *(const f16x8*)(As + (wr * 64 + i * 16 + (lane & 15)) * 32 + (lane >> 4) * 8);
#pragma unroll
    for (int i = 0; i < 4; ++i)
      bfv[i] = *(const f16x8*)(Bs + (wc * 64 + i * 16 + (lane & 15)) * 32 + (lane >> 4) * 8);
#pragma unroll
    for (int i = 0; i < 4; ++i)
#pragma unroll
      for (int j = 0; j < 4; ++j)
        acc[i][j] = __builtin_amdgcn_mfma_f32_16x16x32_f16(af[i], bfv[j], acc[i][j], 0, 0, 0);
  }

#pragma unroll
  for (int i = 0; i < 4; ++i) {
    int r0 = m0 + wr * 64 + i * 16 + (lane >> 4) * 4;
#pragma unroll
    for (int e = 0; e < 4; ++e) {
      float scl = 0.25f / l[r0 + e];
#pragma unroll
      for (int j = 0; j < 4; ++j) {
        int c = n0 + wc * 64 + j * 16 + (lane & 15);
        atomicAdd(&C[(size_t)(r0 + e) * ldc + c], acc[i][j][e] * scl);
      }
    }
  }
}

__global__ __launch_bounds__(256)
void cast_f32_f16(const float* __restrict__ in, u16* __restrict__ out, int n)
{
  int i = (blockIdx.x * 256 + threadIdx.x) * 8;
  if (i >= n) return;
  f32x4 a = *(const f32x4*)(in + i), b = *(const f32x4*)(in + i + 4);
  u16x8 s;
  s[0] = f2h(a[0]); s[1] = f2h(a[1]); s[2] = f2h(a[2]); s[3] = f2h(a[3]);
  s[4] = f2h(b[0]); s[5] = f2h(b[1]); s[6] = f2h(b[2]); s[7] = f2h(b[3]);
  *(u16x8*)(out + i) = s;
}

// out[c][r] = f16(in[r][c]);  64x64 tiles
__global__ __launch_bounds__(256)
void transpose_cast_f32(const float* __restrict__ in, int ldi,
                        u16* __restrict__ out, int ldo)
{
  __shared__ u16 t[64][72];
  int r0 = blockIdx.x * 64, c0 = blockIdx.y * 64;
  int t8 = threadIdx.x & 7, rr = threadIdx.x >> 3;
#pragma unroll
  for (int p = 0; p < 2; ++p) {
    int r = rr + p * 32;
    const float* src = in + (size_t)(r0 + r) * ldi + c0 + t8 * 8;
    f32x4 a = *(const f32x4*)src, b = *(const f32x4*)(src + 4);
    u16x8 s;
    s[0] = f2h(a[0]); s[1] = f2h(a[1]); s[2] = f2h(a[2]); s[3] = f2h(a[3]);
    s[4] = f2h(b[0]); s[5] = f2h(b[1]); s[6] = f2h(b[2]); s[7] = f2h(b[3]);
    *(u16x8*)&t[r][t8 * 8] = s;
  }
  __syncthreads();
#pragma unroll
  for (int p = 0; p < 2; ++p) {
    int c = rr + p * 32;
    u16x8 s;
#pragma unroll
    for (int j = 0; j < 8; ++j) s[j] = t[t8 * 8 + j][c];
    *(u16x8*)(out + (size_t)(c0 + c) * ldo + r0 + t8 * 8) = s;
  }
}

__global__ __launch_bounds__(256)
void transpose_f16(const u16* __restrict__ in, int ldi,
                   u16* __restrict__ out, int ldo)
{
  __shared__ u16 t[64][72];
  int r0 = blockIdx.x * 64, c0 = blockIdx.y * 64;
  int t8 = threadIdx.x & 7, rr = threadIdx.x >> 3;
#pragma unroll
  for (int p = 0; p < 2; ++p) {
    int r = rr + p * 32;
    *(u16x8*)&t[r][t8 * 8] = *(const u16x8*)(in + (size_t)(r0 + r) * ldi + c0 + t8 * 8);
  }
  __syncthreads();
#pragma unroll
  for (int p = 0; p < 2; ++p) {
    int c = rr + p * 32;
    u16x8 s;
#pragma unroll
    for (int j = 0; j < 8; ++j) s[j] = t[t8 * 8 + j][c];
    *(u16x8*)(out + (size_t)(c0 + c) * ldo + r0 + t8 * 8) = s;
  }
}

extern "C" void kernel_launch(void* const* d_in, const int* in_sizes, int n_in,
                              void* d_out, int out_size, void* d_ws, size_t ws_size,
                              hipStream_t stream)
{
  const float* x_k    = (const float*)d_in[0];
  const float* x_q    = (const float*)d_in[1];
  const float* k_w    = (const float*)d_in[2];
  const float* q_w    = (const float*)d_in[3];
  const float* attn_w = (const float*)d_in[4];
  const float* proj_w = (const float*)d_in[5];
  float* out0 = (float*)d_out;                 // doubles as aggk accumulator
  float* out1 = out0 + (size_t)NT * D;         // doubles as aggq accumulator

  char* wptr = (char*)d_ws;
  auto alloc = [&](size_t bytes) { char* p = wptr; wptr += (bytes + 255) & ~(size_t)255; return p; };
  u16*   pb     = (u16*)  alloc((size_t)D * D * 2);
  u16*   pbT    = (u16*)  alloc((size_t)D * D * 2);
  u16*   XKall  = (u16*)  alloc((size_t)NT * NH * D * 2);   // [4096][2048]
  u16*   XKTall = (u16*)  alloc((size_t)NT * NH * D * 2);   // [2048][4096]
  u16*   XQTall = (u16*)  alloc((size_t)NT * NH * D * 2);   // [2048][4096]
  u16*   Kpall  = (u16*)  alloc((size_t)NH * NT * D * 2);   // [4][4096][512]
  u16*   P1     = (u16*)  alloc((size_t)NT * NT * 2);       // row-softmax numerators
  u16*   P2T    = (u16*)  alloc((size_t)NT * NT * 2);       // col-softmax numerators, transposed
  u32*   rowm_u = (u32*)  alloc((size_t)NT * 4);
  u32*   colm_u = (u32*)  alloc((size_t)NT * 4);            // contiguous with rowm_u
  float* rowl   = (float*)alloc((size_t)NT * 4);
  float* csum   = (float*)alloc((size_t)NT * 4);
  float* psumR  = (float*)alloc((size_t)32 * NT * 4);
  float* psumC  = (float*)alloc((size_t)32 * NT * 4);
  char*  Sreg   = alloc((size_t)NT * NT * 2);               // S f16; prep scratch aliased below
  u16*   S      = (u16*)Sreg;
  // prep-only scratch aliased into the (not yet used) S region (30MB <= 32MB)
  char* sp = Sreg;
  auto salloc = [&](size_t bytes) { char* p = sp; sp += (bytes + 255) & ~(size_t)255; return p; };
  u16* xkb   = (u16*)salloc((size_t)NT * D * 2);
  u16* xqb   = (u16*)salloc((size_t)NT * D * 2);
  u16* kwb   = (u16*)salloc((size_t)NH * D * D * 2);
  u16* qwb   = (u16*)salloc((size_t)NH * D * D * 2);
  u16* Abf   = (u16*)salloc((size_t)NH * D * D * 2);
  u16* XQall = (u16*)salloc((size_t)NT * NH * D * 2);

  // ---- prep: casts + projections (all heads batched) ----
  cast_f32_f16<<<NT * D / 2048, 256, 0, stream>>>(x_k, xkb, NT * D);
  cast_f32_f16<<<NT * D / 2048, 256, 0, stream>>>(x_q, xqb, NT * D);
  cast_f32_f16<<<NH * D * D / 2048, 256, 0, stream>>>(k_w, kwb, NH * D * D);
  cast_f32_f16<<<NH * D * D / 2048, 256, 0, stream>>>(q_w, qwb, NH * D * D);
  cast_f32_f16<<<NH * D * D / 2048, 256, 0, stream>>>(attn_w, Abf, NH * D * D);
  cast_f32_f16<<<D * D / 2048, 256, 0, stream>>>(proj_w, pb, D * D);
  transpose_cast_f32<<<dim3(D / 64, D / 64), 256, 0, stream>>>(proj_w, D, pbT, D);

  gemm_bt<OUT_F16><<<dim3(NH * D / 128, NT / 128), 256, 0, stream>>>(
      xkb, D, 0, kwb, D, 0, XKall, NH * D, 0, nullptr, D, nullptr, nullptr);
  gemm_bt<OUT_F16><<<dim3(NH * D / 128, NT / 128), 256, 0, stream>>>(
      xqb, D, 0, qwb, D, 0, XQall, NH * D, 0, nullptr, D, nullptr, nullptr);
  transpose_f16<<<dim3(NT / 64, NH * D / 64), 256, 0, stream>>>(XKall, NH * D, XKTall, NT);
  transpose_f16<<<dim3(NT / 64, NH * D / 64), 256, 0, stream>>>(XQall, NH * D, XQTall, NT);
  gemm_bt<OUT_F16><<<dim3(D / 128, NT / 128, NH), 256, 0, stream>>>(
      XQall, NH * D, (size_t)D, Abf, D, (size_t)D * D, Kpall, D, (size_t)NT * D, nullptr, D,
      nullptr, nullptr);

  hipMemsetAsync(d_out, 0, (size_t)2 * NT * D * 4, stream);   // aggk+aggq accumulators

  // ---- per-head ----
  for (int h = 0; h < NH; ++h) {
    const u16* XKh  = XKall + (size_t)h * D;          // lda 2048
    const u16* XKTh = XKTall + (size_t)h * D * NT;    // ldb 4096
    const u16* XQTh = XQTall + (size_t)h * D * NT;
    const u16* Kph  = Kpall + (size_t)h * NT * D;     // ldb 512

    hipMemsetAsync(rowm_u, 0, (size_t)NT * 4 * 2, stream);    // rowm_u + colm_u

    // S = XK_h @ Kp_h^T  (f16) + row/col maxes
    gemm_bt<OUT_SMAX><<<dim3(NT / 128, NT / 128), 256, 0, stream>>>(
        XKh, NH * D, 0, Kph, D, 0, S, NT, 0, nullptr, D, rowm_u, colm_u);

    // P1, P2T + partial sums in one pass over S
    makeP<<<dim3(NT / 128, NT / 128), 256, 0, stream>>>(S, rowm_u, colm_u, P1, P2T, psumR, psumC);
    sum_reduce<<<NT / 256, 256, 0, stream>>>(psumR, psumC, rowl, csum);

    // dir1: aggk += P1 @ XQ_h / (4*rowsum);  dir2: aggq += P2T @ XK_h / (4*colsum)
    gemm_ps<<<dim3(D / 128, NT / 128, KS), 256, 0, stream>>>(
        P1, NT, XQTh, NT, out0, D, rowl, NT / KS);
    gemm_ps<<<dim3(D / 128, NT / 128, KS), 256, 0, stream>>>(
        P2T, NT, XKTh, NT, out1, D, csum, NT / KS);
  }

  // ---- final projections + residual ----
  u16* kf16 = P1;
  u16* qf16 = P1 + (size_t)NT * D;
  cast_f32_f16<<<NT * D / 2048, 256, 0, stream>>>(out0, kf16, NT * D);
  cast_f32_f16<<<NT * D / 2048, 256, 0, stream>>>(out1, qf16, NT * D);
  gemm_bt<OUT_RES><<<dim3(D / 128, NT / 128), 256, 0, stream>>>(
      kf16, D, 0, pb, D, 0, out0, D, 0, x_k, D, nullptr, nullptr);
  gemm_bt<OUT_RES><<<dim3(D / 128, NT / 128), 256, 0, stream>>>(
      qf16, D, 0, pbT, D, 0, out1, D, 0, x_q, D, nullptr, nullptr);
}